// Round 1
// 452.446 us; speedup vs baseline: 1.0327x; 1.0327x over previous
//
#include <hip/hip_runtime.h>
#include <hip/hip_bf16.h>

// Problem constants (match reference)
#define BB 4
#define SS 4096
#define DM 4096
#define DF 512
#define LN_EPS 1e-5f
#define NORM_EPS 1e-12f
#define SNR 0.3f   // TARGET_SNR * CONFIDENCE * INERTIA

// Workspace layout (float offsets)
#define WS_H     0        // B*DF   = 2048 floats
#define WS_PROJ  2048     // B*DM   = 16384 floats
#define WS_PSUM  18432    // 4096 floats (per-block |proj|^2 partials)
#define WS_SCALE 22528    // B floats
#define WS_RMS   22532    // B floats
#define WS_LAST  22536    // B ints (stored in float buffer via int view)

__device__ __forceinline__ float block_reduce_sum(float v, float* sm) {
    // 256 threads = 4 waves of 64
    for (int off = 32; off > 0; off >>= 1) v += __shfl_down(v, off, 64);
    int wid = threadIdx.x >> 6, lane = threadIdx.x & 63;
    __syncthreads();                 // protect sm from previous reduction
    if (lane == 0) sm[wid] = v;
    __syncthreads();
    return sm[0] + sm[1] + sm[2] + sm[3];
}

// One block per batch row: last index, LayerNorm(h), host RMS at last token.
__global__ __launch_bounds__(256) void k_prep(const float* __restrict__ x,
                                              const float* __restrict__ ff,
                                              const int*   __restrict__ mask,
                                              const float* __restrict__ gamma,
                                              const float* __restrict__ beta,
                                              float* __restrict__ ws) {
    __shared__ float sm[4];
    const int r = blockIdx.x, tid = threadIdx.x;

    // ---- last[r] = max(1, sum(mask[r,:])) - 1
    int ms = 0;
    for (int i = tid; i < SS; i += 256) ms += mask[r * SS + i];
    float msum = block_reduce_sum((float)ms, sm);   // exact: <= 4096
    int last = max(1, (int)(msum + 0.5f)) - 1;

    // ---- LayerNorm over DF=512 (two elements per thread), two-pass
    float f0 = ff[r * DF + tid];
    float f1 = ff[r * DF + tid + 256];
    float mu = block_reduce_sum(f0 + f1, sm) * (1.0f / DF);
    float d0 = f0 - mu, d1 = f1 - mu;
    float var = block_reduce_sum(d0 * d0 + d1 * d1, sm) * (1.0f / DF);
    float inv = rsqrtf(var + LN_EPS);
    ws[WS_H + r * DF + tid]       = d0 * inv * gamma[tid]       + beta[tid];
    ws[WS_H + r * DF + tid + 256] = d1 * inv * gamma[tid + 256] + beta[tid + 256];

    // ---- RMS of x[r, last, :]
    const float4* xr = (const float4*)(x + ((size_t)r * SS + (size_t)last) * DM);
    float ss = 0.0f;
    for (int i = tid; i < DM / 4; i += 256) {
        float4 v = xr[i];
        ss += v.x * v.x + v.y * v.y + v.z * v.z + v.w * v.w;
    }
    ss = block_reduce_sum(ss, sm);
    if (tid == 0) {
        ws[WS_RMS + r] = sqrtf(ss * (1.0f / DM));
        ((int*)ws)[WS_LAST + r] = last;
    }
}

// proj[r,j] = dot(h[r,:], W[j,:]) + b[j]; one wave per output j.
// 4096 blocks x 256 threads (4 waves/block); blocks never straddle rows.
__global__ __launch_bounds__(256) void k_proj(const float* __restrict__ W,
                                              const float* __restrict__ bvec,
                                              float* __restrict__ ws) {
    const int tid = threadIdx.x;
    const int wid = tid >> 6, lane = tid & 63;
    const int jg = blockIdx.x * 4 + wid;      // global output index [0, B*DM)
    const int r = jg >> 12;                   // DM = 4096 = 2^12
    const int j = jg & (DM - 1);

    const float4* wrow = (const float4*)(W + (size_t)j * DF);   // 128 float4
    const float4* hrow = (const float4*)(ws + WS_H + r * DF);
    float4 w0 = wrow[lane], w1 = wrow[lane + 64];
    float4 h0 = hrow[lane], h1 = hrow[lane + 64];
    float dot = w0.x * h0.x + w0.y * h0.y + w0.z * h0.z + w0.w * h0.w
              + w1.x * h1.x + w1.y * h1.y + w1.z * h1.z + w1.w * h1.w;
    for (int off = 32; off > 0; off >>= 1) dot += __shfl_down(dot, off, 64);

    __shared__ float sp[4];
    if (lane == 0) {
        float p = dot + bvec[j];
        ws[WS_PROJ + jg] = p;
        sp[wid] = p * p;
    }
    __syncthreads();
    if (tid == 0) ws[WS_PSUM + blockIdx.x] = sp[0] + sp[1] + sp[2] + sp[3];
}

// Reduce 1024 partials/row -> scale[r] = rms*SNR / max(||proj||, eps)
__global__ __launch_bounds__(256) void k_scale(float* __restrict__ ws) {
    const int tid = threadIdx.x;
    const int r = tid >> 6, lane = tid & 63;   // wave w handles row w
    float s = 0.0f;
    for (int i = lane; i < 1024; i += 64) s += ws[WS_PSUM + r * 1024 + i];
    for (int off = 32; off > 0; off >>= 1) s += __shfl_down(s, off, 64);
    if (lane == 0) {
        float norm = sqrtf(s);
        ws[WS_SCALE + r] = ws[WS_RMS + r] * SNR / fmaxf(norm, NORM_EPS);
    }
}

// Fused bulk copy + hot-row patch. One float4 per thread over the whole
// tensor; replaces the SDMA hipMemcpyAsync (575 GB/s) with a compute-queue
// copy (~6.3 TB/s achievable, cf. fillBufferAligned at 6.5 TB/s on-chip).
// out[r,s,:] = x[r,s,:] + (s == last[r] ? proj[r,:]*scale[r] : 0)
__global__ __launch_bounds__(256) void k_copy_patch(const float* __restrict__ x,
                                                    float* __restrict__ out,
                                                    const float* __restrict__ ws) {
    const size_t idx = (size_t)blockIdx.x * 256 + threadIdx.x;  // float4 index
    const size_t e = idx << 2;                                  // float index
    const int r = (int)(e >> 24);              // SS*DM = 2^24 floats per row
    const int s = (int)((e >> 12) & (SS - 1)); // DM = 2^12
    float4 v = *(const float4*)(x + e);
    const int last = ((const int*)ws)[WS_LAST + r];
    if (s == last) {   // wave-uniform: a wave spans 256 floats within one row
        const int j = (int)(e & (DM - 1));
        const float sc = ws[WS_SCALE + r];
        float4 p = *(const float4*)(ws + WS_PROJ + (r << 12) + j);
        v.x += p.x * sc;
        v.y += p.y * sc;
        v.z += p.z * sc;
        v.w += p.w * sc;
    }
    *(float4*)(out + e) = v;
}

extern "C" void kernel_launch(void* const* d_in, const int* in_sizes, int n_in,
                              void* d_out, int out_size, void* d_ws, size_t ws_size,
                              hipStream_t stream) {
    const float* x     = (const float*)d_in[0];
    const float* ff    = (const float*)d_in[1];
    // d_in[2] = token_ids (int64) — unused by reference (trigger_ids empty)
    const int*   mask  = (const int*)d_in[3];
    const float* gamma = (const float*)d_in[4];
    const float* beta  = (const float*)d_in[5];
    const float* W     = (const float*)d_in[6];
    const float* bvec  = (const float*)d_in[7];
    float* out = (float*)d_out;
    float* ws  = (float*)d_ws;

    // 1) per-row prep: last, LayerNorm h, host RMS
    k_prep<<<BB, 256, 0, stream>>>(x, ff, mask, gamma, beta, ws);
    // 2) projection + norm partials
    k_proj<<<(BB * DM) / 4, 256, 0, stream>>>(W, bvec, ws);
    // 3) finalize scale
    k_scale<<<1, 256, 0, stream>>>(ws);
    // 4) fused copy + patch: (B*S*DM/4) float4s / 256 threads = 65536 blocks
    k_copy_patch<<<(BB * SS * DM) / (4 * 256), 256, 0, stream>>>(x, out, ws);
}